// Round 16
// baseline (602.338 us; speedup 1.0000x reference)
//
#include <hip/hip_runtime.h>

// AttackLSTM R16 — 13-wave fused pipeline with quad-chunk (low-VGPR) waves.
// R12-R15 lesson: allocator caps arch VGPRs at 128, parks overflow in AGPRs
// (v_dot2 can't source AGPRs -> per-use copies; forcing arch -> scratch).
// Fix: every wave fits in 128 arch regs via the R9/R10-verified quad layout
// (lane (q,hid): 4 gate-rows x 16-elem k-chunk, 3-DPP rotate-reduce).
//   waves 0-3 : a0 rec (hh-dot, x scalar)     t=v
//   waves 4-7 : a1 rec + fused ih-dot(h_a0)   t=v-1
//   waves 8-11: a2 rec + fused ih-dot(h_a1)   t=v-2
//   wave 12   : b0 row-dot + b0/b1/b2 chain   t=v-3
// h exchanged via parity-double-buffered fp16 LDS; 1 lgkm barrier/interval.

#define BB 256
#define TT 512

typedef _Float16 v2h __attribute__((ext_vector_type(2)));

__device__ __forceinline__ float sig_(float x) {
  return __builtin_amdgcn_rcpf(1.f + __builtin_amdgcn_exp2f(-1.44269504f * x));
}
__device__ __forceinline__ float tanh_(float x) {
  return __builtin_fmaf(2.f, __builtin_amdgcn_rcpf(1.f + __builtin_amdgcn_exp2f(-2.88539008f * x)), -1.f);
}

template <int K>
__device__ __forceinline__ float qb_(float v) {
  return __int_as_float(__builtin_amdgcn_update_dpp(
      0, __float_as_int(v), (K | (K << 2) | (K << 4) | (K << 6)), 0xF, 0xF, true));
}
// quad rotate: lane i reads lane (i-D)&3 (verified R9/R10).
template <int CTRL>
__device__ __forceinline__ float qrot_(float v) {
  return __int_as_float(__builtin_amdgcn_update_dpp(
      0, __float_as_int(v), CTRL, 0xF, 0xF, true));
}

__device__ __forceinline__ void ldsbar_() {
  asm volatile("s_waitcnt lgkmcnt(0)\n\ts_barrier" ::: "memory");
}

#if __has_builtin(__builtin_amdgcn_fdot2)
#define FDOT2(acc, a, b) (acc) = __builtin_amdgcn_fdot2((a), (b), (acc), false)
#else
#define FDOT2(acc, a, b) \
  (acc) = __builtin_fmaf((float)(a)[0], (float)(b)[0], \
          __builtin_fmaf((float)(a)[1], (float)(b)[1], (acc)))
#endif

__device__ __forceinline__ v2h bc2h_(int v) { return __builtin_bit_cast(v2h, v); }

// chunk [16q,16q+16) of fp32 row -> 8 v2h
__device__ __forceinline__ void load_chunk8(const float* W, int row, int q, v2h d[8]) {
  const float4* p = reinterpret_cast<const float4*>(W + row * 64 + 16 * q);
#pragma unroll
  for (int i = 0; i < 4; ++i) {
    float4 v = p[i];
    d[2 * i]     = v2h{(_Float16)v.x, (_Float16)v.y};
    d[2 * i + 1] = v2h{(_Float16)v.z, (_Float16)v.w};
  }
}

// chunk [16q,16q+16) of a 64-half LDS vector -> 8 v2h (2x ds_read_b128)
__device__ __forceinline__ void load_chunk_h(const _Float16* vec, int q, v2h hx[8]) {
  const int4* p = reinterpret_cast<const int4*>(vec + 16 * q);
  int4 b0 = p[0], b1 = p[1];
  hx[0] = bc2h_(b0.x); hx[1] = bc2h_(b0.y); hx[2] = bc2h_(b0.z); hx[3] = bc2h_(b0.w);
  hx[4] = bc2h_(b1.x); hx[5] = bc2h_(b1.y); hx[6] = bc2h_(b1.z); hx[7] = bc2h_(b1.w);
}

// full 64-half LDS vector -> 32 v2h (8x ds_read_b128), for the b-wave
__device__ __forceinline__ void load_h64(const _Float16* p, v2h hv[32]) {
  const int4* hp = reinterpret_cast<const int4*>(p);
#pragma unroll
  for (int i = 0; i < 8; ++i) {
    int4 blk = hp[i];
    hv[4 * i + 0] = bc2h_(blk.x);
    hv[4 * i + 1] = bc2h_(blk.y);
    hv[4 * i + 2] = bc2h_(blk.z);
    hv[4 * i + 3] = bc2h_(blk.w);
  }
}

// quad rotate-reduce: pre(own row q) = base + a0 + rot1(a1)+rot2(a2)+rot3(a3)
__device__ __forceinline__ float qcomb_(float base, float a0, float a1, float a2, float a3) {
  float pre = base + a0;
  pre += qrot_<0x93>(a1);
  pre += qrot_<0x4E>(a2);
  pre += qrot_<0x39>(a3);
  return pre;
}

// own-gate activation + quad gather + c/h update (lane's gate = q)
__device__ __forceinline__ float lstm_upd_(float pre, int q, float& c) {
  float sc = (q == 2) ? -2.88539008f : -1.44269504f;
  float e = __builtin_amdgcn_exp2f(sc * pre);
  float r = __builtin_amdgcn_rcpf(1.f + e);
  float act = (q == 2) ? __builtin_fmaf(2.f, r, -1.f) : r;
  float gi = qb_<0>(act);
  float gf = qb_<1>(act);
  float gg = qb_<2>(act);
  float go = qb_<3>(act);
  c = __builtin_fmaf(gf, c, gi * gg);
  return go * tanh_(c);
}

__global__ __attribute__((amdgpu_flat_work_group_size(832, 832),
                          amdgpu_waves_per_eu(4, 4)))
void lstm_pipe_k(
    const float* __restrict__ x,
    const float* __restrict__ wih_a0, const float* __restrict__ whh_a0,
    const float* __restrict__ bih_a0, const float* __restrict__ bhh_a0,
    const float* __restrict__ wih_a1, const float* __restrict__ whh_a1,
    const float* __restrict__ bih_a1, const float* __restrict__ bhh_a1,
    const float* __restrict__ wih_a2, const float* __restrict__ whh_a2,
    const float* __restrict__ bih_a2, const float* __restrict__ bhh_a2,
    const float* __restrict__ wih_b0, const float* __restrict__ whh_b0,
    const float* __restrict__ bih_b0, const float* __restrict__ bhh_b0,
    const float* __restrict__ wih_b1, const float* __restrict__ whh_b1,
    const float* __restrict__ bih_b1, const float* __restrict__ bhh_b1,
    const float* __restrict__ wih_b2, const float* __restrict__ whh_b2,
    const float* __restrict__ bih_b2, const float* __restrict__ bhh_b2,
    float* __restrict__ out)  // [B,T]
{
  const int b = blockIdx.x;
  const int tid = threadIdx.x;
  const int wave = tid >> 6;
  const int lane = tid & 63;
  const int q = lane & 3;        // quad position = k-chunk = own gate row
  const int hid16 = lane >> 2;   // hid within wave's 16-slice

  __shared__ _Float16 hh[3 * 2 * 64];  // [layer][parity][hid]
  __shared__ float xs[TT];

  for (int i = tid; i < TT; i += 832) xs[i] = x[(size_t)b * TT + i];
  if (tid < 384) reinterpret_cast<int*>(hh)[tid] = 0;

  // per-wave weight registers
  v2h wH[4][8];  // hh chunks (groups A/B/C) | b-wave: wH flat = full wih_b0 row
  v2h wI[4][8];  // ih chunks (groups B/C)
  float bias = 0.f, wi0 = 0.f;
  float whb0[4] = {}, wi1b[4] = {}, wh1b[4] = {}, bb1[4] = {},
        wi2b[4] = {}, wh2b[4] = {}, bb2[4] = {};

  if (wave < 4) {  // A: a0
    const int hid = wave * 16 + hid16;
    const int row = q * 64 + hid;
#pragma unroll
    for (int d = 0; d < 4; ++d)
      load_chunk8(whh_a0, ((q + d) & 3) * 64 + hid, q, wH[d]);
    bias = bih_a0[row] + bhh_a0[row];
    wi0 = wih_a0[row];
  } else if (wave < 8) {  // B: a1
    const int hid = (wave - 4) * 16 + hid16;
    const int row = q * 64 + hid;
#pragma unroll
    for (int d = 0; d < 4; ++d) {
      load_chunk8(whh_a1, ((q + d) & 3) * 64 + hid, q, wH[d]);
      load_chunk8(wih_a1, ((q + d) & 3) * 64 + hid, q, wI[d]);
    }
    bias = bih_a1[row] + bhh_a1[row];
  } else if (wave < 12) {  // C: a2
    const int hid = (wave - 8) * 16 + hid16;
    const int row = q * 64 + hid;
#pragma unroll
    for (int d = 0; d < 4; ++d) {
      load_chunk8(whh_a2, ((q + d) & 3) * 64 + hid, q, wH[d]);
      load_chunk8(wih_a2, ((q + d) & 3) * 64 + hid, q, wI[d]);
    }
    bias = bih_a2[row] + bhh_a2[row];
  } else {  // b-wave
    // full wih_b0 row for this lane's gate (lane&3), as 32 v2h in wH flat
    const float4* p = reinterpret_cast<const float4*>(wih_b0 + q * 64);
    v2h* flat = &wH[0][0];
#pragma unroll
    for (int i = 0; i < 16; ++i) {
      float4 v = p[i];
      flat[2 * i]     = v2h{(_Float16)v.x, (_Float16)v.y};
      flat[2 * i + 1] = v2h{(_Float16)v.z, (_Float16)v.w};
    }
    bias = bih_b0[q] + bhh_b0[q];
#pragma unroll
    for (int k = 0; k < 4; ++k) {
      whb0[k] = whh_b0[k];
      wi1b[k] = wih_b1[k]; wh1b[k] = whh_b1[k]; bb1[k] = bih_b1[k] + bhh_b1[k];
      wi2b[k] = wih_b2[k]; wh2b[k] = whh_b2[k]; bb2[k] = bih_b2[k] + bhh_b2[k];
    }
  }
  __syncthreads();

  float c = 0.f;  // rec cell state (replicated across quad)
  float h0b = 0.f, c0b = 0.f, h1b = 0.f, c1b = 0.f, h2b = 0.f, c2b = 0.f;

  for (int v = 0; v < TT + 3; ++v) {
    if (wave < 4) {  // A: a0 rec, t=v
      const int t = v;
      if (t < TT) {
        const int hid = wave * 16 + hid16;
        v2h hx[8];
        load_chunk_h(hh + 0 * 128 + ((t + 1) & 1) * 64, q, hx);  // h_a0(t-1)
        float a0 = 0.f, a1 = 0.f, a2 = 0.f, a3 = 0.f;
#pragma unroll
        for (int j = 0; j < 8; ++j) {
          FDOT2(a0, wH[0][j], hx[j]); FDOT2(a1, wH[1][j], hx[j]);
          FDOT2(a2, wH[2][j], hx[j]); FDOT2(a3, wH[3][j], hx[j]);
        }
        float base = __builtin_fmaf(wi0, xs[t], bias);
        float pre = qcomb_(base, a0, a1, a2, a3);
        float h = lstm_upd_(pre, q, c);
        if (q == 0) hh[0 * 128 + (t & 1) * 64 + hid] = (_Float16)h;
      }
    } else if (wave < 8) {  // B: a1 rec + ih, t=v-1
      const int t = v - 1;
      if (t >= 0 && t < TT) {
        const int hid = (wave - 4) * 16 + hid16;
        v2h hp[8], ho[8];
        load_chunk_h(hh + 0 * 128 + (t & 1) * 64, q, hp);        // h_a0(t)
        load_chunk_h(hh + 1 * 128 + ((t + 1) & 1) * 64, q, ho);  // h_a1(t-1)
        float a0 = 0.f, a1 = 0.f, a2 = 0.f, a3 = 0.f;
#pragma unroll
        for (int j = 0; j < 8; ++j) {
          FDOT2(a0, wI[0][j], hp[j]); FDOT2(a1, wI[1][j], hp[j]);
          FDOT2(a2, wI[2][j], hp[j]); FDOT2(a3, wI[3][j], hp[j]);
        }
#pragma unroll
        for (int j = 0; j < 8; ++j) {
          FDOT2(a0, wH[0][j], ho[j]); FDOT2(a1, wH[1][j], ho[j]);
          FDOT2(a2, wH[2][j], ho[j]); FDOT2(a3, wH[3][j], ho[j]);
        }
        float pre = qcomb_(bias, a0, a1, a2, a3);
        float h = lstm_upd_(pre, q, c);
        if (q == 0) hh[1 * 128 + (t & 1) * 64 + hid] = (_Float16)h;
      }
    } else if (wave < 12) {  // C: a2 rec + ih, t=v-2
      const int t = v - 2;
      if (t >= 0 && t < TT) {
        const int hid = (wave - 8) * 16 + hid16;
        v2h hp[8], ho[8];
        load_chunk_h(hh + 1 * 128 + (t & 1) * 64, q, hp);        // h_a1(t)
        load_chunk_h(hh + 2 * 128 + ((t + 1) & 1) * 64, q, ho);  // h_a2(t-1)
        float a0 = 0.f, a1 = 0.f, a2 = 0.f, a3 = 0.f;
#pragma unroll
        for (int j = 0; j < 8; ++j) {
          FDOT2(a0, wI[0][j], hp[j]); FDOT2(a1, wI[1][j], hp[j]);
          FDOT2(a2, wI[2][j], hp[j]); FDOT2(a3, wI[3][j], hp[j]);
        }
#pragma unroll
        for (int j = 0; j < 8; ++j) {
          FDOT2(a0, wH[0][j], ho[j]); FDOT2(a1, wH[1][j], ho[j]);
          FDOT2(a2, wH[2][j], ho[j]); FDOT2(a3, wH[3][j], ho[j]);
        }
        float pre = qcomb_(bias, a0, a1, a2, a3);
        float h = lstm_upd_(pre, q, c);
        if (q == 0) hh[2 * 128 + (t & 1) * 64 + hid] = (_Float16)h;
      }
    } else {  // b-wave, t=v-3
      const int t = v - 3;
      if (t >= 0 && t < TT) {
        v2h hv[32];
        load_h64(hh + 2 * 128 + (t & 1) * 64, hv);  // h_a2(t)
        float pg = bias;
        const v2h* flat = &wH[0][0];
#pragma unroll
        for (int j = 0; j < 32; ++j) FDOT2(pg, flat[j], hv[j]);
        float p_i = qb_<0>(pg), p_f = qb_<1>(pg), p_g = qb_<2>(pg), p_o = qb_<3>(pg);
        float i0 = sig_(__builtin_fmaf(whb0[0], h0b, p_i));
        float f0 = sig_(__builtin_fmaf(whb0[1], h0b, p_f));
        float g0 = tanh_(__builtin_fmaf(whb0[2], h0b, p_g));
        float o0 = sig_(__builtin_fmaf(whb0[3], h0b, p_o));
        c0b = __builtin_fmaf(f0, c0b, i0 * g0);
        h0b = o0 * tanh_(c0b);
        float i1 = sig_(bb1[0] + __builtin_fmaf(wi1b[0], h0b, wh1b[0] * h1b));
        float f1 = sig_(bb1[1] + __builtin_fmaf(wi1b[1], h0b, wh1b[1] * h1b));
        float g1 = tanh_(bb1[2] + __builtin_fmaf(wi1b[2], h0b, wh1b[2] * h1b));
        float o1 = sig_(bb1[3] + __builtin_fmaf(wi1b[3], h0b, wh1b[3] * h1b));
        c1b = __builtin_fmaf(f1, c1b, i1 * g1);
        h1b = o1 * tanh_(c1b);
        float i2 = sig_(bb2[0] + __builtin_fmaf(wi2b[0], h1b, wh2b[0] * h2b));
        float f2 = sig_(bb2[1] + __builtin_fmaf(wi2b[1], h1b, wh2b[1] * h2b));
        float g2 = tanh_(bb2[2] + __builtin_fmaf(wi2b[2], h1b, wh2b[2] * h2b));
        float o2 = sig_(bb2[3] + __builtin_fmaf(wi2b[3], h1b, wh2b[3] * h2b));
        c2b = __builtin_fmaf(f2, c2b, i2 * g2);
        h2b = o2 * tanh_(c2b);
        if (lane == 0) out[(size_t)b * TT + t] = h2b;
      }
    }
    ldsbar_();
  }
}

extern "C" void kernel_launch(void* const* d_in, const int* in_sizes, int n_in,
                              void* d_out, int out_size, void* d_ws, size_t ws_size,
                              hipStream_t stream) {
  const float* x      = (const float*)d_in[0];
  const float* wih_a0 = (const float*)d_in[1];
  const float* whh_a0 = (const float*)d_in[2];
  const float* bih_a0 = (const float*)d_in[3];
  const float* bhh_a0 = (const float*)d_in[4];
  const float* wih_a1 = (const float*)d_in[5];
  const float* whh_a1 = (const float*)d_in[6];
  const float* bih_a1 = (const float*)d_in[7];
  const float* bhh_a1 = (const float*)d_in[8];
  const float* wih_a2 = (const float*)d_in[9];
  const float* whh_a2 = (const float*)d_in[10];
  const float* bih_a2 = (const float*)d_in[11];
  const float* bhh_a2 = (const float*)d_in[12];
  const float* wih_b0 = (const float*)d_in[13];
  const float* whh_b0 = (const float*)d_in[14];
  const float* bih_b0 = (const float*)d_in[15];
  const float* bhh_b0 = (const float*)d_in[16];
  const float* wih_b1 = (const float*)d_in[17];
  const float* whh_b1 = (const float*)d_in[18];
  const float* bih_b1 = (const float*)d_in[19];
  const float* bhh_b1 = (const float*)d_in[20];
  const float* wih_b2 = (const float*)d_in[21];
  const float* whh_b2 = (const float*)d_in[22];
  const float* bih_b2 = (const float*)d_in[23];
  const float* bhh_b2 = (const float*)d_in[24];
  float* out = (float*)d_out;

  lstm_pipe_k<<<BB, 832, 0, stream>>>(
      x,
      wih_a0, whh_a0, bih_a0, bhh_a0,
      wih_a1, whh_a1, bih_a1, bhh_a1,
      wih_a2, whh_a2, bih_a2, bhh_a2,
      wih_b0, whh_b0, bih_b0, bhh_b0,
      wih_b1, whh_b1, bih_b1, bhh_b1,
      wih_b2, whh_b2, bih_b2, bhh_b2,
      out);
}